// Round 7
// baseline (180.144 us; speedup 1.0000x reference)
//
#include <hip/hip_runtime.h>
#include <stdint.h>

#define EPS 1e-8f

typedef __attribute__((ext_vector_type(8))) __bf16 bf16x8;
typedef __attribute__((ext_vector_type(4))) float f32x4;

static constexpr int BO = 6400;   // B*O
static constexpr int AA = 16;     // attributes
static constexpr int DD = 1024;   // D
static constexpr int HH = 512;    // H

// ---------- helpers ----------
__device__ __forceinline__ unsigned short f2bf(float x) {
    uint32_t b = __float_as_uint(x);
    b += 0x7fffu + ((b >> 16) & 1u);   // round-to-nearest-even (finite inputs)
    return (unsigned short)(b >> 16);
}

__device__ __forceinline__ float fast_tanh(float x) {
    float e = __expf(2.0f * x);
    return 1.0f - __fdividef(2.0f, e + 1.0f);
}

// async 1KB DMA: 64 lanes x 16B global -> LDS[ldsbase + lane*16], no landing VGPRs
__device__ __forceinline__ void async16(void* lds, const void* g) {
    __builtin_amdgcn_global_load_lds(
        (const __attribute__((address_space(1))) unsigned int*)g,
        (__attribute__((address_space(3))) unsigned int*)lds, 16, 0, 0);
}

// ---------- kernel 1: f32 -> bf16 staging of W_obj only ----------
__global__ __launch_bounds__(256) void k_prep_w(const float* __restrict__ W,
                                                unsigned short* __restrict__ W_bf) {
    const int i = blockIdx.x * 256 + threadIdx.x;   // 65536 8-elem units
    const long off = (long)i * 8;
    float4 v0 = *(const float4*)(W + off);
    float4 v1 = *(const float4*)(W + off + 4);
    union { unsigned short u[8]; int4 v; } pk;
    pk.u[0] = f2bf(v0.x); pk.u[1] = f2bf(v0.y); pk.u[2] = f2bf(v0.z); pk.u[3] = f2bf(v0.w);
    pk.u[4] = f2bf(v1.x); pk.u[5] = f2bf(v1.y); pk.u[6] = f2bf(v1.z); pk.u[7] = f2bf(v1.w);
    *(int4*)(W_bf + off) = pk.v;
}

// ---------- kernel 2: att_obj = obj @ W^T + b_obj, f32 out (unchanged, ~14 us) ----------
__global__ __launch_bounds__(256) void k_gemm(const float* __restrict__ obj,
                                              const unsigned short* __restrict__ W_bf,
                                              const float* __restrict__ b_obj,
                                              float* __restrict__ att_obj) {
    const int wv   = threadIdx.x >> 6;
    const int lane = threadIdx.x & 63;
    const int xcd  = blockIdx.x & 7;
    const int j    = blockIdx.x >> 3;
    const int mt   = xcd * 13 + (j % 13);
    if (mt >= 100) return;
    const int nt   = j / 13;
    const int m0   = mt * 64 + wv * 16;
    const int n0   = nt * 64;
    const int lr   = lane & 15;
    const int lk   = (lane >> 4) * 8;

    const float*          ap = obj  + (size_t)(m0 + lr) * DD + lk;
    const unsigned short* bp = W_bf + (size_t)(n0 + lr) * DD + lk;

    f32x4 acc[4];
    #pragma unroll
    for (int jj = 0; jj < 4; ++jj) acc[jj] = f32x4{0.f, 0.f, 0.f, 0.f};

    float4 a_lo = *(const float4*)(ap);
    float4 a_hi = *(const float4*)(ap + 4);
    bf16x8 bfr[4];
    #pragma unroll
    for (int jj = 0; jj < 4; ++jj) bfr[jj] = *(const bf16x8*)(bp + (size_t)jj * 16 * DD);

    #pragma unroll 1
    for (int k0 = 0; k0 < DD; k0 += 32) {
        const int kn = (k0 + 32 < DD) ? (k0 + 32) : 0;
        float4 na_lo = *(const float4*)(ap + kn);
        float4 na_hi = *(const float4*)(ap + kn + 4);
        bf16x8 nb[4];
        #pragma unroll
        for (int jj = 0; jj < 4; ++jj) nb[jj] = *(const bf16x8*)(bp + (size_t)jj * 16 * DD + kn);

        bf16x8 afr;
        afr[0] = (__bf16)a_lo.x; afr[1] = (__bf16)a_lo.y;
        afr[2] = (__bf16)a_lo.z; afr[3] = (__bf16)a_lo.w;
        afr[4] = (__bf16)a_hi.x; afr[5] = (__bf16)a_hi.y;
        afr[6] = (__bf16)a_hi.z; afr[7] = (__bf16)a_hi.w;
        #pragma unroll
        for (int jj = 0; jj < 4; ++jj)
            acc[jj] = __builtin_amdgcn_mfma_f32_16x16x32_bf16(afr, bfr[jj], acc[jj], 0, 0, 0);

        a_lo = na_lo; a_hi = na_hi;
        #pragma unroll
        for (int jj = 0; jj < 4; ++jj) bfr[jj] = nb[jj];
    }

    const int crow = (lane >> 4) * 4;
    #pragma unroll
    for (int jj = 0; jj < 4; ++jj) {
        const int n = n0 + jj * 16 + lr;
        const float bb = b_obj[n];
        #pragma unroll
        for (int r = 0; r < 4; ++r)
            att_obj[(size_t)(m0 + crow + r) * HH + n] = acc[jj][r] + bb;
    }
}

// ---------- kernel 3: fused attn via LDS DMA staging ----------
// ONE BLOCK (256 thr, 4 waves) PER ROW. global_load_lds gives register-free reads:
// a wave keeps up to 16 KB in flight (no landing VGPRs), 2 blocks/CU -> ~100 KB/CU
// outstanding, vs ~2-5 KB with normal loads (the r3-r6 2-4 TB/s ceiling).
// LDS: pbuf [16][512] f32 (32 KB, recycled for attr chunk B) | abuf [8][1024] (32 KB)
// | s_sc[16]. Wave w: stages+scores attrs 4w..4w+3; stages attrA 2w,2w+1 and
// attrB 8+2w,9+2w (attrB lands exactly in wave w's own consumed p-slots).
__global__ __launch_bounds__(256) void k_attn(const float* __restrict__ att_obj,   // [6400][512] f32
                                              const float* __restrict__ p_attr,    // [6400][16][512]
                                              const int* __restrict__ masks,       // [6400][16]
                                              const float* __restrict__ w_alpha,   // [512]
                                              const float* __restrict__ attr_feats,// [6400][16][1024]
                                              float* __restrict__ out) {           // [6400][1024]
    __shared__ __align__(16) char smem[65664];
    float* pbuf = (float*)smem;              // [16][512] f32; later attrB [8][1024]
    float* abuf = (float*)(smem + 32768);    // [8][1024] f32
    float* s_sc = (float*)(smem + 65536);    // [16]

    const int row  = blockIdx.x;
    const int tid  = threadIdx.x;
    const int wv   = tid >> 6;
    const int lane = tid & 63;

    // masks -> bitmask (block-uniform values)
    int mbits;
    {
        const int4* m4 = (const int4*)(masks + (size_t)row * AA);
        int4 a = m4[0], b = m4[1], c = m4[2], d = m4[3];
        mbits =  (a.x)      | (a.y << 1)  | (a.z << 2)  | (a.w << 3)
              | (b.x << 4) | (b.y << 5)  | (b.z << 6)  | (b.w << 7)
              | (c.x << 8) | (c.y << 9)  | (c.z << 10) | (c.w << 11)
              | (d.x << 12)| (d.y << 13) | (d.z << 14) | (d.w << 15);
    }

    const float* prow = p_attr     + (size_t)row * AA * HH;
    const float* arow = attr_feats + (size_t)row * AA * DD;

    // issue p DMAs (wave w: attrs 4w..4w+3, 2 x 1KB each, skip masked)
    #pragma unroll
    for (int q = 0; q < 4; ++q) {
        const int a = wv * 4 + q;
        if (mbits & (1 << a)) {
            async16(pbuf + a * HH,       prow + a * HH       + lane * 4);
            async16(pbuf + a * HH + 256, prow + a * HH + 256 + lane * 4);
        }
    }
    // issue attr chunk A DMAs (wave w: attrs 2w, 2w+1; 4 x 1KB each)
    #pragma unroll
    for (int q = 0; q < 2; ++q) {
        const int a = wv * 2 + q;
        if (mbits & (1 << a)) {
            #pragma unroll
            for (int j = 0; j < 4; ++j)
                async16(abuf + a * DD + j * 256, arow + (size_t)a * DD + j * 256 + lane * 4);
        }
    }

    // att_obj / w_alpha into regs while DMAs fly: lane covers h = lane*8 .. +7
    const f32x4* att4 = (const f32x4*)(att_obj + (size_t)row * HH);
    const f32x4* wa4  = (const f32x4*)w_alpha;
    const f32x4 av0 = att4[2 * lane], av1 = att4[2 * lane + 1];
    const f32x4 wv0 = wa4[2 * lane],  wv1 = wa4[2 * lane + 1];

    asm volatile("s_waitcnt vmcnt(0)" ::: "memory");   // own p + attrA in LDS

    // scores for own attrs (full-wave: 8 h-vals/lane, 6-step butterfly)
    #pragma unroll
    for (int q = 0; q < 4; ++q) {
        const int a = wv * 4 + q;
        if (mbits & (1 << a)) {
            const f32x4* pr = (const f32x4*)(pbuf + a * HH);
            f32x4 x0 = pr[2 * lane], x1 = pr[2 * lane + 1];
            float s;
            s  = wv0.x * fast_tanh(x0.x + av0.x);
            s += wv0.y * fast_tanh(x0.y + av0.y);
            s += wv0.z * fast_tanh(x0.z + av0.z);
            s += wv0.w * fast_tanh(x0.w + av0.w);
            s += wv1.x * fast_tanh(x1.x + av1.x);
            s += wv1.y * fast_tanh(x1.y + av1.y);
            s += wv1.z * fast_tanh(x1.z + av1.z);
            s += wv1.w * fast_tanh(x1.w + av1.w);
            s += __shfl_xor(s, 1);
            s += __shfl_xor(s, 2);
            s += __shfl_xor(s, 4);
            s += __shfl_xor(s, 8);
            s += __shfl_xor(s, 16);
            s += __shfl_xor(s, 32);
            if (lane == 0) s_sc[a] = s;
        } else {
            if (lane == 0) s_sc[a] = 0.f;
        }
    }

    // guard: own p ds_reads fully retired before DMA-overwriting the same bytes
    asm volatile("s_waitcnt lgkmcnt(0)" ::: "memory");

    // issue attr chunk B DMAs into own recycled p-slots (attrs 8+2w, 9+2w)
    #pragma unroll
    for (int q = 0; q < 2; ++q) {
        const int a = 8 + wv * 2 + q;
        if (mbits & (1 << a)) {
            #pragma unroll
            for (int j = 0; j < 4; ++j)
                async16(pbuf + (a - 8) * DD + j * 256, arow + (size_t)a * DD + j * 256 + lane * 4);
        }
    }

    __syncthreads();   // s_sc + abuf (chunk A) now valid block-wide

    // softmax + masked renorm, replicated per thread (b_alpha cancels; masked e = 0,
    // so denom = T + EPS*S_full ~= T*(1+EPS), rel err ~2e-8)
    float wgt[AA];
    {
        float sc[AA];
        #pragma unroll
        for (int a = 0; a < AA; ++a) sc[a] = s_sc[a];
        float mx = -3.0e38f;
        #pragma unroll
        for (int a = 0; a < AA; ++a)
            if (mbits & (1 << a)) mx = fmaxf(mx, sc[a]);
        float T = 0.f;
        #pragma unroll
        for (int a = 0; a < AA; ++a) {
            float e = (mbits & (1 << a)) ? __expf(sc[a] - mx) : 0.f;
            wgt[a] = e;
            T += e;
        }
        const float inv = (T > 0.f) ? 1.0f / (T * (1.0f + EPS)) : 0.f;
        #pragma unroll
        for (int a = 0; a < AA; ++a) wgt[a] *= inv;
    }

    // pool chunk A: thread owns d = tid*4..+3. Branch-guard masked slots
    // (their LDS bytes are unstaged garbage -> may be NaN; must not touch).
    f32x4 acc = {0.f, 0.f, 0.f, 0.f};
    #pragma unroll
    for (int a = 0; a < 8; ++a) {
        if (mbits & (1 << a)) {
            f32x4 v = *(const f32x4*)(abuf + a * DD + tid * 4);
            acc += wgt[a] * v;
        }
    }

    asm volatile("s_waitcnt vmcnt(0)" ::: "memory");   // own attrB drained
    __syncthreads();                                    // chunk B valid block-wide

    #pragma unroll
    for (int a = 8; a < AA; ++a) {
        if (mbits & (1 << a)) {
            f32x4 v = *(const f32x4*)(pbuf + (a - 8) * DD + tid * 4);
            acc += wgt[a] * v;
        }
    }
    *(f32x4*)(out + (size_t)row * DD + tid * 4) = acc;
}

extern "C" void kernel_launch(void* const* d_in, const int* in_sizes, int n_in,
                              void* d_out, int out_size, void* d_ws, size_t ws_size,
                              hipStream_t stream) {
    const float* obj_vecs   = (const float*)d_in[0];
    const float* attr_feats = (const float*)d_in[1];
    const float* p_attr     = (const float*)d_in[2];
    const int*   masks      = (const int*)d_in[3];
    const float* W_obj      = (const float*)d_in[4];
    const float* b_obj      = (const float*)d_in[5];
    const float* w_alpha    = (const float*)d_in[6];
    // d_in[7] = b_alpha: uniform additive shift before softmax -> cancels exactly
    float* out = (float*)d_out;

    char* ws = (char*)d_ws;
    float*          att_obj = (float*)ws;                       // 13,107,200 B
    unsigned short* W_bf    = (unsigned short*)(ws + 13107200); //  1,048,576 B
    // total ws use: 14,155,776 B

    k_prep_w<<<256, 256, 0, stream>>>(W_obj, W_bf);
    k_gemm<<<832, 256, 0, stream>>>(obj_vecs, W_bf, b_obj, att_obj);
    k_attn<<<BO, 256, 0, stream>>>(att_obj, p_attr, masks, w_alpha, attr_feats, out);
}

// Round 8
// 171.780 us; speedup vs baseline: 1.0487x; 1.0487x over previous
//
#include <hip/hip_runtime.h>
#include <stdint.h>

#define EPS 1e-8f

typedef __attribute__((ext_vector_type(8))) __bf16 bf16x8;
typedef __attribute__((ext_vector_type(4))) float f32x4;

static constexpr int BO = 6400;   // B*O
static constexpr int AA = 16;     // attributes
static constexpr int DD = 1024;   // D
static constexpr int HH = 512;    // H

// ---------- helpers ----------
__device__ __forceinline__ unsigned short f2bf(float x) {
    uint32_t b = __float_as_uint(x);
    b += 0x7fffu + ((b >> 16) & 1u);   // round-to-nearest-even (finite inputs)
    return (unsigned short)(b >> 16);
}

__device__ __forceinline__ float fast_tanh(float x) {
    float e = __expf(2.0f * x);
    return 1.0f - __fdividef(2.0f, e + 1.0f);
}

// ---------- kernel 1: f32 -> bf16 staging of W_obj only ----------
__global__ __launch_bounds__(256) void k_prep_w(const float* __restrict__ W,
                                                unsigned short* __restrict__ W_bf) {
    const int i = blockIdx.x * 256 + threadIdx.x;   // 65536 8-elem units
    const long off = (long)i * 8;
    float4 v0 = *(const float4*)(W + off);
    float4 v1 = *(const float4*)(W + off + 4);
    union { unsigned short u[8]; int4 v; } pk;
    pk.u[0] = f2bf(v0.x); pk.u[1] = f2bf(v0.y); pk.u[2] = f2bf(v0.z); pk.u[3] = f2bf(v0.w);
    pk.u[4] = f2bf(v1.x); pk.u[5] = f2bf(v1.y); pk.u[6] = f2bf(v1.z); pk.u[7] = f2bf(v1.w);
    *(int4*)(W_bf + off) = pk.v;
}

// ---------- kernel 2: att_obj = obj @ W^T + b_obj, f32 out (unchanged, ~13 us) ----------
__global__ __launch_bounds__(256) void k_gemm(const float* __restrict__ obj,
                                              const unsigned short* __restrict__ W_bf,
                                              const float* __restrict__ b_obj,
                                              float* __restrict__ att_obj) {
    const int wv   = threadIdx.x >> 6;
    const int lane = threadIdx.x & 63;
    const int xcd  = blockIdx.x & 7;
    const int j    = blockIdx.x >> 3;
    const int mt   = xcd * 13 + (j % 13);
    if (mt >= 100) return;
    const int nt   = j / 13;
    const int m0   = mt * 64 + wv * 16;
    const int n0   = nt * 64;
    const int lr   = lane & 15;
    const int lk   = (lane >> 4) * 8;

    const float*          ap = obj  + (size_t)(m0 + lr) * DD + lk;
    const unsigned short* bp = W_bf + (size_t)(n0 + lr) * DD + lk;

    f32x4 acc[4];
    #pragma unroll
    for (int jj = 0; jj < 4; ++jj) acc[jj] = f32x4{0.f, 0.f, 0.f, 0.f};

    float4 a_lo = *(const float4*)(ap);
    float4 a_hi = *(const float4*)(ap + 4);
    bf16x8 bfr[4];
    #pragma unroll
    for (int jj = 0; jj < 4; ++jj) bfr[jj] = *(const bf16x8*)(bp + (size_t)jj * 16 * DD);

    #pragma unroll 1
    for (int k0 = 0; k0 < DD; k0 += 32) {
        const int kn = (k0 + 32 < DD) ? (k0 + 32) : 0;
        float4 na_lo = *(const float4*)(ap + kn);
        float4 na_hi = *(const float4*)(ap + kn + 4);
        bf16x8 nb[4];
        #pragma unroll
        for (int jj = 0; jj < 4; ++jj) nb[jj] = *(const bf16x8*)(bp + (size_t)jj * 16 * DD + kn);

        bf16x8 afr;
        afr[0] = (__bf16)a_lo.x; afr[1] = (__bf16)a_lo.y;
        afr[2] = (__bf16)a_lo.z; afr[3] = (__bf16)a_lo.w;
        afr[4] = (__bf16)a_hi.x; afr[5] = (__bf16)a_hi.y;
        afr[6] = (__bf16)a_hi.z; afr[7] = (__bf16)a_hi.w;
        #pragma unroll
        for (int jj = 0; jj < 4; ++jj)
            acc[jj] = __builtin_amdgcn_mfma_f32_16x16x32_bf16(afr, bfr[jj], acc[jj], 0, 0, 0);

        a_lo = na_lo; a_hi = na_hi;
        #pragma unroll
        for (int jj = 0; jj < 4; ++jj) bfr[jj] = nb[jj];
    }

    const int crow = (lane >> 4) * 4;
    #pragma unroll
    for (int jj = 0; jj < 4; ++jj) {
        const int n = n0 + jj * 16 + lr;
        const float bb = b_obj[n];
        #pragma unroll
        for (int r = 0; r < 4; ++r)
            att_obj[(size_t)(m0 + crow + r) * HH + n] = acc[jj][r] + bb;
    }
}

// ---------- kernel 3: fused attn, ADDRESS-REDIRECT mask skip ----------
// ONE WAVE PER ROW, 4 rows/block, no LDS/barriers — r3's exact instruction stream
// (same load count, same batching, same VALU). The ONLY change vs r3: masked attrs'
// load addresses are redirected to the first unmasked attr's region (a0), which is
// fetched anyway -> masked loads become L1/L2 hits, halving HBM FETCH without
// touching issue structure. Masked values are finite reals; x * 0.0f == 0 exact.
// This is the controlled test: bytes halve, everything else identical to r3.
__global__ __launch_bounds__(256) void k_attn(const float* __restrict__ att_obj,   // [6400][512] f32
                                              const float* __restrict__ p_attr,    // [6400][16][512]
                                              const int* __restrict__ masks,       // [6400][16]
                                              const float* __restrict__ w_alpha,   // [512]
                                              const float* __restrict__ attr_feats,// [6400][16][1024]
                                              float* __restrict__ out) {           // [6400][1024]
    const int wv   = threadIdx.x >> 6;
    const int lane = threadIdx.x & 63;
    const int row  = blockIdx.x * 4 + wv;

    // masks -> bitmask; a0 = first unmasked attr (redirect target)
    int mbits;
    {
        const int4* m4 = (const int4*)(masks + (size_t)row * AA);
        int4 a = m4[0], b = m4[1], c = m4[2], d = m4[3];
        mbits =  (a.x)      | (a.y << 1)  | (a.z << 2)  | (a.w << 3)
              | (b.x << 4) | (b.y << 5)  | (b.z << 6)  | (b.w << 7)
              | (c.x << 8) | (c.y << 9)  | (c.z << 10) | (c.w << 11)
              | (d.x << 12)| (d.y << 13) | (d.z << 14) | (d.w << 15);
    }
    const int a0 = mbits ? __builtin_ctz(mbits) : 0;

    // per-lane att_obj / w_alpha slices (w_alpha L2-hot)
    const f32x4* att4 = (const f32x4*)(att_obj + (size_t)row * HH);
    const f32x4* wa4  = (const f32x4*)w_alpha;
    const f32x4 av0 = att4[lane],      av1 = att4[64 + lane];
    const f32x4 wv0 = wa4[lane],       wv1 = wa4[64 + lane];

    const float* prow = p_attr     + (size_t)row * AA * HH;
    const float* arow = attr_feats + (size_t)row * AA * DD;

    // phase 1: per-attr partial dot — unconditional compute, redirected addresses
    float sc[AA];
    #pragma unroll 4
    for (int a = 0; a < AA; ++a) {
        const float* pa = prow + (size_t)((mbits & (1 << a)) ? a : a0) * HH;
        f32x4 x0 = ((const f32x4*)pa)[lane];
        f32x4 x1 = ((const f32x4*)pa)[64 + lane];
        float s;
        s  = wv0.x * fast_tanh(x0.x + av0.x);
        s += wv0.y * fast_tanh(x0.y + av0.y);
        s += wv0.z * fast_tanh(x0.z + av0.z);
        s += wv0.w * fast_tanh(x0.w + av0.w);
        s += wv1.x * fast_tanh(x1.x + av1.x);
        s += wv1.y * fast_tanh(x1.y + av1.y);
        s += wv1.z * fast_tanh(x1.z + av1.z);
        s += wv1.w * fast_tanh(x1.w + av1.w);
        sc[a] = s;
    }

    // cross-lane butterfly (all 16, unconditional — identical to r3)
    #pragma unroll
    for (int d = 1; d < 64; d <<= 1) {
        #pragma unroll
        for (int a = 0; a < AA; ++a) sc[a] += __shfl_xor(sc[a], d);
    }

    // phase 2: softmax over unmasked + renorm, lane-local (b_alpha cancels).
    // masked e == 0 -> denom = T + EPS*S_full ~= T*(1+EPS), rel err <~2e-7.
    float mx = -3.0e38f;
    #pragma unroll
    for (int a = 0; a < AA; ++a)
        if (mbits & (1 << a)) mx = fmaxf(mx, sc[a]);
    float T = 0.f;
    float wgt[AA];
    #pragma unroll
    for (int a = 0; a < AA; ++a) {
        float e = (mbits & (1 << a)) ? __expf(sc[a] - mx) : 0.f;
        wgt[a] = e;
        T += e;
    }
    const float inv = (T > 0.f) ? 1.0f / (T * (1.0f + EPS)) : 0.f;
    #pragma unroll
    for (int a = 0; a < AA; ++a) wgt[a] *= inv;

    // phase 3: streaming weighted pooling — unconditional, redirected addresses.
    // masked: finite redirected values * exact 0.0 weight = 0 contribution.
    f32x4 acc0 = {0.f,0.f,0.f,0.f}, acc1 = acc0, acc2 = acc0, acc3 = acc0;
    #pragma unroll 4
    for (int a = 0; a < AA; ++a) {
        const float* aa = arow + (size_t)((mbits & (1 << a)) ? a : a0) * DD;
        const f32x4* a4 = (const f32x4*)aa;
        f32x4 v0 = a4[       lane];
        f32x4 v1 = a4[ 64 + lane];
        f32x4 v2 = a4[128 + lane];
        f32x4 v3 = a4[192 + lane];
        const float w = wgt[a];
        acc0 += w * v0;
        acc1 += w * v1;
        acc2 += w * v2;
        acc3 += w * v3;
    }
    f32x4* o4 = (f32x4*)(out + (size_t)row * DD);
    o4[      lane] = acc0;
    o4[ 64 + lane] = acc1;
    o4[128 + lane] = acc2;
    o4[192 + lane] = acc3;
}

extern "C" void kernel_launch(void* const* d_in, const int* in_sizes, int n_in,
                              void* d_out, int out_size, void* d_ws, size_t ws_size,
                              hipStream_t stream) {
    const float* obj_vecs   = (const float*)d_in[0];
    const float* attr_feats = (const float*)d_in[1];
    const float* p_attr     = (const float*)d_in[2];
    const int*   masks      = (const int*)d_in[3];
    const float* W_obj      = (const float*)d_in[4];
    const float* b_obj      = (const float*)d_in[5];
    const float* w_alpha    = (const float*)d_in[6];
    // d_in[7] = b_alpha: uniform additive shift before softmax -> cancels exactly
    float* out = (float*)d_out;

    char* ws = (char*)d_ws;
    float*          att_obj = (float*)ws;                       // 13,107,200 B
    unsigned short* W_bf    = (unsigned short*)(ws + 13107200); //  1,048,576 B
    // total ws use: 14,155,776 B

    k_prep_w<<<256, 256, 0, stream>>>(W_obj, W_bf);
    k_gemm<<<832, 256, 0, stream>>>(obj_vecs, W_bf, b_obj, att_obj);
    k_attn<<<BO / 4, 256, 0, stream>>>(att_obj, p_attr, masks, w_alpha, attr_feats, out);
}